// Round 20
// baseline (373.007 us; speedup 1.0000x reference)
//
#include <hip/hip_runtime.h>
#include <math.h>

// ---------------------------------------------------------------------------
// GAT IoT classifier — round 20.
// r19 base (361.6 µs). GEMM grid (2,My)->(My): one block covers ALL 4 head-
// column blocks — A staged exactly once (r19 still re-read A 2x). 16 MFMAs
// per barrier-pair, LDS 25.6 KB, acc 64 VGPR (~16 waves/CU — acceptable for
// a streaming GEMM with deep per-wave ILP, unlike the random-gather agg).
// Aggregate: online-softmax, 66.8 µs, ~87% of compulsory 8-XCD sweep (floor).
// ---------------------------------------------------------------------------

typedef __attribute__((ext_vector_type(8))) _Float16 half8v;  // 8 fp16 (4 VGPRs)
typedef __attribute__((ext_vector_type(4))) float f32x4;

__device__ __forceinline__ float lrelu(float x) { return x > 0.f ? x : 0.2f * x; }
__device__ __forceinline__ float elu1(float x) { return x > 0.f ? x : (__expf(x) - 1.f); }

// ---------------- weights -> transposed fp16 + indeg zeroing, one launch ------
__global__ void convert_weights_kernel(const float* __restrict__ W1, const float* __restrict__ W2,
                                       const float* __restrict__ lw1,
                                       _Float16* __restrict__ o1, _Float16* __restrict__ o2,
                                       _Float16* __restrict__ o3, int* __restrict__ indeg,
                                       int N) {
  int t = blockIdx.x * blockDim.x + threadIdx.x;
  if (t < 32768) {                       // W1
    int n = t >> 7, k = t & 127;
    o1[t] = (_Float16)W1[(long)k * 256 + n];
  } else if (t < 98304) {                // W2
    int i = t - 32768;
    int n = i >> 8, k = i & 255;
    o2[i] = (_Float16)W2[(long)k * 256 + n];
  } else if (t < 114688) {               // lw1
    int i = t - 98304;
    int n = i >> 8, k = i & 255;
    o3[i] = (_Float16)lw1[(long)k * 64 + n];
  } else if (t < 114688 + N) {           // indeg zeroing
    indeg[t - 114688] = 0;
  }
}

// ---------------- CSR build ----------------
__global__ void count_kernel(const int* __restrict__ dst, int E, int* __restrict__ indeg) {
  int e = blockIdx.x * blockDim.x + threadIdx.x;
  if (e < E) atomicAdd(&indeg[dst[e]], 1);
}

__global__ void scan_block_kernel(const int* __restrict__ in, int* __restrict__ incl,
                                  int* __restrict__ bsum, int N) {
  __shared__ int wsum[16];
  int gid = blockIdx.x * 1024 + threadIdx.x;
  int lane = threadIdx.x & 63, w = threadIdx.x >> 6;
  int v = (gid < N) ? in[gid] : 0;
  int sv = v;
#pragma unroll
  for (int o = 1; o < 64; o <<= 1) {
    int t = __shfl_up(sv, o);
    if (lane >= o) sv += t;
  }
  if (lane == 63) wsum[w] = sv;
  __syncthreads();
  if (w == 0) {
    int bs = (lane < 16) ? wsum[lane] : 0;
#pragma unroll
    for (int o = 1; o < 16; o <<= 1) {
      int t = __shfl_up(bs, o);
      if (lane >= o) bs += t;
    }
    if (lane < 16) wsum[lane] = bs;
  }
  __syncthreads();
  if (w > 0) sv += wsum[w - 1];
  if (gid < N) incl[gid] = sv;
  if (threadIdx.x == 1023) bsum[blockIdx.x] = sv;
}

__global__ void scan_finalize_kernel(const int* __restrict__ in, const int* __restrict__ incl,
                                     const int* __restrict__ bsum, int* __restrict__ off,
                                     int* __restrict__ cursor, int N) {
  int gid = blockIdx.x * blockDim.x + threadIdx.x;
  if (gid >= N) return;
  int b = gid >> 10;
  int carry = 0;
  for (int k = 0; k < b; ++k) carry += bsum[k];
  int ic = incl[gid] + carry;
  off[gid + 1] = ic;
  cursor[gid] = ic - in[gid];
  if (gid == 0) off[0] = 0;
}

__global__ void fill_kernel(const int* __restrict__ src, const int* __restrict__ dst, int E,
                            int* __restrict__ cursor, int* __restrict__ csr_src) {
  int e = blockIdx.x * blockDim.x + threadIdx.x;
  if (e < E) {
    int pos = atomicAdd(&cursor[dst[e]], 1);
    csr_src[pos] = src[e];
  }
}

// ---------------- fp16 MFMA GEMM (all 4 head blocks/block) + attn epilogue ----
// C[M,256] = A[M,K] x W[K,256]; W transposed [256][K]. One block covers cols
// [0,256): A staged once, four B tiles, 16 MFMAs per barrier-pair.
template <typename AT>
__launch_bounds__(256)
__global__ void mfma_gemm_attn_kernel(const AT* __restrict__ A,
                                      const _Float16* __restrict__ B,
                                      const float* __restrict__ att_s,
                                      const float* __restrict__ att_d,
                                      _Float16* __restrict__ C,
                                      float* __restrict__ a_s, float* __restrict__ a_d,
                                      int M, int K) {
  __shared__ _Float16 As[64][40];     // 5.1 KB
  __shared__ _Float16 Bs[4][64][40];  // 20.5 KB
  int tid = threadIdx.x;
  int bm = blockIdx.x * 64;
  int lane = tid & 63, wave = tid >> 6;
  int srow = tid >> 2, sch = (tid & 3) * 8;
  const AT* Ap = A + (long)(bm + srow) * K + sch;
  const _Float16* Bp = B + (long)srow * K + sch;
  bool arow_ok = (bm + srow) < M;
  int fm = lane & 15, fq = lane >> 4;
  f32x4 acc[4][4];
#pragma unroll
  for (int t = 0; t < 4; ++t)
#pragma unroll
    for (int cb = 0; cb < 4; ++cb) acc[t][cb] = (f32x4){0.f, 0.f, 0.f, 0.f};
  for (int k0 = 0; k0 < K; k0 += 32) {
    half8v a8 = {0, 0, 0, 0, 0, 0, 0, 0};
    if (arow_ok) {
      if constexpr (sizeof(AT) == 4) {
        float4 f0 = *(const float4*)(Ap + k0);
        float4 f1 = *(const float4*)(Ap + k0 + 4);
        a8 = (half8v){(_Float16)f0.x, (_Float16)f0.y, (_Float16)f0.z, (_Float16)f0.w,
                      (_Float16)f1.x, (_Float16)f1.y, (_Float16)f1.z, (_Float16)f1.w};
      } else {
        a8 = *(const half8v*)(Ap + k0);
      }
    }
    uint4 vb0 = *(const uint4*)(Bp + (long)0 * 64 * K + k0);
    uint4 vb1 = *(const uint4*)(Bp + (long)1 * 64 * K + k0);
    uint4 vb2 = *(const uint4*)(Bp + (long)2 * 64 * K + k0);
    uint4 vb3 = *(const uint4*)(Bp + (long)3 * 64 * K + k0);
    *(half8v*)&As[srow][sch] = a8;
    *(uint4*)&Bs[0][srow][sch] = vb0;
    *(uint4*)&Bs[1][srow][sch] = vb1;
    *(uint4*)&Bs[2][srow][sch] = vb2;
    *(uint4*)&Bs[3][srow][sch] = vb3;
    __syncthreads();
    half8v ah = *(const half8v*)&As[wave * 16 + fm][fq * 8];
#pragma unroll
    for (int t = 0; t < 4; ++t)
#pragma unroll
      for (int cb = 0; cb < 4; ++cb) {
        half8v bh = *(const half8v*)&Bs[t][cb * 16 + fm][fq * 8];
        acc[t][cb] = __builtin_amdgcn_mfma_f32_16x16x32_f16(ah, bh, acc[t][cb], 0, 0, 0);
      }
    __syncthreads();
  }
  int row0 = bm + wave * 16 + fq * 4;
#pragma unroll
  for (int t = 0; t < 4; ++t) {
    int cbase = t * 64;
    float asv[4], adv[4];
#pragma unroll
    for (int cb = 0; cb < 4; ++cb) {
      int col = cbase + cb * 16 + fm;
      asv[cb] = att_s[col];
      adv[cb] = att_d[col];
    }
#pragma unroll
    for (int r = 0; r < 4; ++r) {
      int row = row0 + r;
      float sp = 0.f, dp = 0.f;
#pragma unroll
      for (int cb = 0; cb < 4; ++cb) {
        float v = acc[t][cb][r];
        sp = fmaf(v, asv[cb], sp);
        dp = fmaf(v, adv[cb], dp);
        if (row < M) C[(long)row * 256 + cbase + cb * 16 + fm] = (_Float16)v;
      }
#pragma unroll
      for (int o = 1; o < 16; o <<= 1) {
        sp += __shfl_xor(sp, o);
        dp += __shfl_xor(dp, o);
      }
      if (fm == 0 && row < M) {
        a_s[(long)row * 4 + t] = sp;
        a_d[(long)row * 4 + t] = dp;
      }
    }
  }
}

// ---------------- fused fp16 MFMA head ----------------
__launch_bounds__(256)
__global__ void head_mfma_kernel(const _Float16* __restrict__ A, const _Float16* __restrict__ B,
                                 const float* __restrict__ lb1, const float* __restrict__ lw2,
                                 const float* __restrict__ lb2, float* __restrict__ out, int M) {
  __shared__ _Float16 As[64][40];
  __shared__ _Float16 Bs[64][40];
  int tid = threadIdx.x;
  int bm = blockIdx.x * 64;
  int lane = tid & 63, wave = tid >> 6;
  int srow = tid >> 2, sch = (tid & 3) * 8;
  const _Float16* Ap = A + (long)(bm + srow) * 256 + sch;
  const _Float16* Bp = B + (long)srow * 256 + sch;
  int fm = lane & 15, fq = lane >> 4;
  f32x4 acc[4];
#pragma unroll
  for (int cb = 0; cb < 4; ++cb) acc[cb] = (f32x4){0.f, 0.f, 0.f, 0.f};
  for (int k0 = 0; k0 < 256; k0 += 32) {
    uint4 va = *(const uint4*)(Ap + k0);
    uint4 vb = *(const uint4*)(Bp + k0);
    *(uint4*)&As[srow][sch] = va;
    *(uint4*)&Bs[srow][sch] = vb;
    __syncthreads();
    half8v ah = *(const half8v*)&As[wave * 16 + fm][fq * 8];
#pragma unroll
    for (int cb = 0; cb < 4; ++cb) {
      half8v bh = *(const half8v*)&Bs[cb * 16 + fm][fq * 8];
      acc[cb] = __builtin_amdgcn_mfma_f32_16x16x32_f16(ah, bh, acc[cb], 0, 0, 0);
    }
    __syncthreads();
  }
  float lb1c[4], w20[4], w21[4];
#pragma unroll
  for (int cb = 0; cb < 4; ++cb) {
    int col = cb * 16 + fm;
    lb1c[cb] = lb1[col];
    w20[cb] = lw2[col * 2 + 0];
    w21[cb] = lw2[col * 2 + 1];
  }
  float b20 = lb2[0], b21 = lb2[1];
#pragma unroll
  for (int r = 0; r < 4; ++r) {
    float v0 = 0.f, v1 = 0.f;
#pragma unroll
    for (int cb = 0; cb < 4; ++cb) {
      float s = fmaxf(acc[cb][r] + lb1c[cb], 0.f);
      v0 = fmaf(s, w20[cb], v0);
      v1 = fmaf(s, w21[cb], v1);
    }
#pragma unroll
    for (int o = 1; o < 16; o <<= 1) {
      v0 += __shfl_xor(v0, o);
      v1 += __shfl_xor(v1, o);
    }
    if (fm == 0) {
      int row = bm + wave * 16 + fq * 4 + r;
      if (row < M) {
        v0 += b20;
        v1 += b21;
        float mx = fmaxf(v0, v1);
        float ls = mx + logf(expf(v0 - mx) + expf(v1 - mx));
        out[(long)row * 2 + 0] = v0 - ls;
        out[(long)row * 2 + 1] = v1 - ls;
      }
    }
  }
}

// ---------------- per-node ONLINE-softmax aggregation, fp16 gather ----------
__launch_bounds__(256)
__global__ void gat_aggregate8_kernel(const _Float16* __restrict__ h,
                                      const float* __restrict__ a_s,
                                      const float* __restrict__ a_d,
                                      const int* __restrict__ off,
                                      const int* __restrict__ csr_src,
                                      const float* __restrict__ bias,
                                      _Float16* __restrict__ outp, int N) {
  int wid = (blockIdx.x * blockDim.x + threadIdx.x) >> 6;
  int lane = threadIdx.x & 63;
  if (wid >= N) return;
  int c = lane & 31, hlf = lane >> 5, head4 = c >> 3;
  int h1 = lane & 3, sl1 = lane >> 2;
  int beg = off[wid], cnt = off[wid + 1] - beg;
  float ad_h1 = a_d[wid * 4 + h1];
  float m = lrelu(a_s[wid * 4 + h1] + ad_h1);  // running max, init = self logit
  float acc[8] = {};
  float z = 0.f;
  if (hlf == 0) {
    z = 1.f;
    half8v sr = *(const half8v*)(h + (long)wid * 256 + c * 8);
#pragma unroll
    for (int i = 0; i < 8; ++i) acc[i] = (float)sr[i];
  }
  for (int c0 = 0; c0 < cnt; c0 += 16) {
    int i2 = c0 + (lane & 15);
    int sv = (i2 < cnt) ? csr_src[beg + i2] : 0;
    int i1 = c0 + sl1;
    int spi = __shfl(sv, sl1);
    float l = (i1 < cnt) ? lrelu(a_s[(long)spi * 4 + h1] + ad_h1) : -1e30f;
    float lm = l;
    lm = fmaxf(lm, __shfl_xor(lm, 4));
    lm = fmaxf(lm, __shfl_xor(lm, 8));
    lm = fmaxf(lm, __shfl_xor(lm, 16));
    lm = fmaxf(lm, __shfl_xor(lm, 32));
    float m_new = fmaxf(m, lm);
    float alpha = __expf(m - m_new);
    float pv = (i1 < cnt) ? __expf(l - m_new) : 0.f;
    m = m_new;
    float alpha4 = __shfl(alpha, head4);
    z *= alpha4;
#pragma unroll
    for (int i = 0; i < 8; ++i) acc[i] *= alpha4;
#pragma unroll 4
    for (int j = 0; j < 16; j += 2) {
      if (c0 + j >= cnt) break;
      int e = j + hlf;
      int s = __shfl(sv, e);
      float p = __shfl(pv, e * 4 + head4);
      z += p;
      half8v rv = *(const half8v*)(h + (long)s * 256 + c * 8);
      acc[0] = fmaf(p, (float)rv[0], acc[0]);
      acc[1] = fmaf(p, (float)rv[1], acc[1]);
      acc[2] = fmaf(p, (float)rv[2], acc[2]);
      acc[3] = fmaf(p, (float)rv[3], acc[3]);
      acc[4] = fmaf(p, (float)rv[4], acc[4]);
      acc[5] = fmaf(p, (float)rv[5], acc[5]);
      acc[6] = fmaf(p, (float)rv[6], acc[6]);
      acc[7] = fmaf(p, (float)rv[7], acc[7]);
    }
  }
  z += __shfl_xor(z, 32);
#pragma unroll
  for (int i = 0; i < 8; ++i) acc[i] += __shfl_xor(acc[i], 32);
  if (hlf == 0) {
    float inv = 1.f / z;
    half8v o;
#pragma unroll
    for (int i = 0; i < 8; ++i) o[i] = (_Float16)elu1(fmaf(acc[i], inv, bias[c * 8 + i]));
    *(half8v*)(outp + (long)wid * 256 + c * 8) = o;
  }
}

// ---------------------------------------------------------------------------
static inline int cdiv(int a, int b) { return (a + b - 1) / b; }

extern "C" void kernel_launch(void* const* d_in, const int* in_sizes, int n_in,
                              void* d_out, int out_size, void* d_ws, size_t ws_size,
                              hipStream_t stream) {
  const float* x = (const float*)d_in[0];
  const int* ei = (const int*)d_in[1];
  const float* W1 = (const float*)d_in[2];
  const float* as1 = (const float*)d_in[3];
  const float* ad1 = (const float*)d_in[4];
  const float* b1 = (const float*)d_in[5];
  const float* W2 = (const float*)d_in[6];
  const float* as2 = (const float*)d_in[7];
  const float* ad2 = (const float*)d_in[8];
  const float* b2 = (const float*)d_in[9];
  const float* lw1 = (const float*)d_in[10];
  const float* lb1 = (const float*)d_in[11];
  const float* lw2 = (const float*)d_in[12];
  const float* lb2 = (const float*)d_in[13];
  float* out = (float*)d_out;

  int N = in_sizes[0] / 128;  // 50000
  int E = in_sizes[1] / 2;    // 800000
  int Mp = cdiv(N, 64) * 64;  // 50048

  char* ws = (char*)d_ws;
  _Float16* Wt1 = (_Float16*)ws; ws += 256 * 128 * 2;
  _Float16* Wt2 = (_Float16*)ws; ws += 256 * 256 * 2;
  _Float16* WL = (_Float16*)ws; ws += 64 * 256 * 2;
  _Float16* C = (_Float16*)ws; ws += (size_t)Mp * 256 * 2;   // GEMM out
  _Float16* h2 = (_Float16*)ws; ws += (size_t)Mp * 256 * 2;  // aggregate out
  float* aS = (float*)ws; ws += (size_t)N * 4 * 4;
  float* aD = (float*)ws; ws += (size_t)N * 4 * 4;
  int* csr_src = (int*)ws; ws += (size_t)E * 4;
  int* indeg = (int*)ws; ws += (size_t)N * 4;
  int* cursor = (int*)ws; ws += (size_t)N * 4;
  int* off = (int*)ws; ws += (size_t)(N + 4) * 4;
  int* incl = (int*)ws; ws += (size_t)N * 4;
  int* bsum = (int*)ws; ws += 64 * 4;

  const int* e_src = ei;
  const int* e_dst = ei + E;
  int nb = cdiv(N, 1024);

  // weight conversion + indeg zeroing (one launch)
  convert_weights_kernel<<<cdiv(114688 + N, 256), 256, 0, stream>>>(W1, W2, lw1, Wt1, Wt2, WL,
                                                                    indeg, N);

  // CSR build
  count_kernel<<<cdiv(E, 256), 256, 0, stream>>>(e_dst, E, indeg);
  scan_block_kernel<<<nb, 1024, 0, stream>>>(indeg, incl, bsum, N);
  scan_finalize_kernel<<<cdiv(N, 256), 256, 0, stream>>>(indeg, incl, bsum, off, cursor, N);
  fill_kernel<<<cdiv(E, 256), 256, 0, stream>>>(e_src, e_dst, E, cursor, csr_src);

  // Layer 1 (A = fp32 x, converted in staging; all 4 head blocks per block)
  mfma_gemm_attn_kernel<float><<<Mp / 64, 256, 0, stream>>>(x, Wt1, as1, ad1, C, aS, aD, N, 128);
  gat_aggregate8_kernel<<<cdiv(N, 4), 256, 0, stream>>>(C, aS, aD, off, csr_src, b1, h2, N);

  // Layer 2
  mfma_gemm_attn_kernel<_Float16><<<Mp / 64, 256, 0, stream>>>(h2, Wt2, as2, ad2, C, aS, aD, N,
                                                               256);
  gat_aggregate8_kernel<<<cdiv(N, 4), 256, 0, stream>>>(C, aS, aD, off, csr_src, b2, h2, N);

  // Head (MFMA, fused epilogue)
  head_mfma_kernel<<<Mp / 64, 256, 0, stream>>>(h2, WL, lb1, lw2, lb2, out, N);
}

// Round 21
// 360.240 us; speedup vs baseline: 1.0354x; 1.0354x over previous
//
#include <hip/hip_runtime.h>
#include <math.h>

// ---------------------------------------------------------------------------
// GAT IoT classifier — round 21 (byte-identical to round-19, the measured
// optimum: 361.6 µs). r20's 4-wide GEMM regressed (+11 µs, occupancy law,
// 4th confirmation). Reuse/occupancy curve fully mapped: 1-wide 373-375,
// 2-wide 361.6 (optimum), 4-wide 373.
// Aggregates at ~87% of compulsory 8-XCD sweep; GEMMs at measured-best.
// ---------------------------------------------------------------------------

typedef __attribute__((ext_vector_type(8))) _Float16 half8v;  // 8 fp16 (4 VGPRs)
typedef __attribute__((ext_vector_type(4))) float f32x4;

__device__ __forceinline__ float lrelu(float x) { return x > 0.f ? x : 0.2f * x; }
__device__ __forceinline__ float elu1(float x) { return x > 0.f ? x : (__expf(x) - 1.f); }

// ---------------- weights -> transposed fp16 + indeg zeroing, one launch ------
__global__ void convert_weights_kernel(const float* __restrict__ W1, const float* __restrict__ W2,
                                       const float* __restrict__ lw1,
                                       _Float16* __restrict__ o1, _Float16* __restrict__ o2,
                                       _Float16* __restrict__ o3, int* __restrict__ indeg,
                                       int N) {
  int t = blockIdx.x * blockDim.x + threadIdx.x;
  if (t < 32768) {                       // W1
    int n = t >> 7, k = t & 127;
    o1[t] = (_Float16)W1[(long)k * 256 + n];
  } else if (t < 98304) {                // W2
    int i = t - 32768;
    int n = i >> 8, k = i & 255;
    o2[i] = (_Float16)W2[(long)k * 256 + n];
  } else if (t < 114688) {               // lw1
    int i = t - 98304;
    int n = i >> 8, k = i & 255;
    o3[i] = (_Float16)lw1[(long)k * 64 + n];
  } else if (t < 114688 + N) {           // indeg zeroing
    indeg[t - 114688] = 0;
  }
}

// ---------------- CSR build ----------------
__global__ void count_kernel(const int* __restrict__ dst, int E, int* __restrict__ indeg) {
  int e = blockIdx.x * blockDim.x + threadIdx.x;
  if (e < E) atomicAdd(&indeg[dst[e]], 1);
}

__global__ void scan_block_kernel(const int* __restrict__ in, int* __restrict__ incl,
                                  int* __restrict__ bsum, int N) {
  __shared__ int wsum[16];
  int gid = blockIdx.x * 1024 + threadIdx.x;
  int lane = threadIdx.x & 63, w = threadIdx.x >> 6;
  int v = (gid < N) ? in[gid] : 0;
  int sv = v;
#pragma unroll
  for (int o = 1; o < 64; o <<= 1) {
    int t = __shfl_up(sv, o);
    if (lane >= o) sv += t;
  }
  if (lane == 63) wsum[w] = sv;
  __syncthreads();
  if (w == 0) {
    int bs = (lane < 16) ? wsum[lane] : 0;
#pragma unroll
    for (int o = 1; o < 16; o <<= 1) {
      int t = __shfl_up(bs, o);
      if (lane >= o) bs += t;
    }
    if (lane < 16) wsum[lane] = bs;
  }
  __syncthreads();
  if (w > 0) sv += wsum[w - 1];
  if (gid < N) incl[gid] = sv;
  if (threadIdx.x == 1023) bsum[blockIdx.x] = sv;
}

__global__ void scan_finalize_kernel(const int* __restrict__ in, const int* __restrict__ incl,
                                     const int* __restrict__ bsum, int* __restrict__ off,
                                     int* __restrict__ cursor, int N) {
  int gid = blockIdx.x * blockDim.x + threadIdx.x;
  if (gid >= N) return;
  int b = gid >> 10;
  int carry = 0;
  for (int k = 0; k < b; ++k) carry += bsum[k];
  int ic = incl[gid] + carry;
  off[gid + 1] = ic;
  cursor[gid] = ic - in[gid];
  if (gid == 0) off[0] = 0;
}

__global__ void fill_kernel(const int* __restrict__ src, const int* __restrict__ dst, int E,
                            int* __restrict__ cursor, int* __restrict__ csr_src) {
  int e = blockIdx.x * blockDim.x + threadIdx.x;
  if (e < E) {
    int pos = atomicAdd(&cursor[dst[e]], 1);
    csr_src[pos] = src[e];
  }
}

// ---------------- fp16 MFMA GEMM (2 head blocks/block) + attn epilogue ----
// C[M,256] = A[M,K] x W[K,256]; W transposed [256][K]. Block covers cols
// [bn, bn+128): A staged once, two B tiles, 8 MFMAs per barrier-pair.
template <typename AT>
__launch_bounds__(256)
__global__ void mfma_gemm_attn_kernel(const AT* __restrict__ A,
                                      const _Float16* __restrict__ B,
                                      const float* __restrict__ att_s,
                                      const float* __restrict__ att_d,
                                      _Float16* __restrict__ C,
                                      float* __restrict__ a_s, float* __restrict__ a_d,
                                      int M, int K) {
  __shared__ _Float16 As[64][40];     // 10.2+5.1 KB total: residency-safe
  __shared__ _Float16 Bs[2][64][40];
  int tid = threadIdx.x;
  int bm = blockIdx.y * 64, bn = blockIdx.x * 128;
  int lane = tid & 63, wave = tid >> 6;
  int srow = tid >> 2, sch = (tid & 3) * 8;
  const AT* Ap = A + (long)(bm + srow) * K + sch;
  const _Float16* Bp0 = B + (long)(bn + srow) * K + sch;
  const _Float16* Bp1 = B + (long)(bn + 64 + srow) * K + sch;
  bool arow_ok = (bm + srow) < M;
  int fm = lane & 15, fq = lane >> 4;
  f32x4 acc[2][4];
#pragma unroll
  for (int t = 0; t < 2; ++t)
#pragma unroll
    for (int cb = 0; cb < 4; ++cb) acc[t][cb] = (f32x4){0.f, 0.f, 0.f, 0.f};
  for (int k0 = 0; k0 < K; k0 += 32) {
    half8v a8 = {0, 0, 0, 0, 0, 0, 0, 0};
    if (arow_ok) {
      if constexpr (sizeof(AT) == 4) {
        float4 f0 = *(const float4*)(Ap + k0);
        float4 f1 = *(const float4*)(Ap + k0 + 4);
        a8 = (half8v){(_Float16)f0.x, (_Float16)f0.y, (_Float16)f0.z, (_Float16)f0.w,
                      (_Float16)f1.x, (_Float16)f1.y, (_Float16)f1.z, (_Float16)f1.w};
      } else {
        a8 = *(const half8v*)(Ap + k0);
      }
    }
    uint4 vb0 = *(const uint4*)(Bp0 + k0);
    uint4 vb1 = *(const uint4*)(Bp1 + k0);
    *(half8v*)&As[srow][sch] = a8;
    *(uint4*)&Bs[0][srow][sch] = vb0;
    *(uint4*)&Bs[1][srow][sch] = vb1;
    __syncthreads();
    half8v ah = *(const half8v*)&As[wave * 16 + fm][fq * 8];
#pragma unroll
    for (int t = 0; t < 2; ++t)
#pragma unroll
      for (int cb = 0; cb < 4; ++cb) {
        half8v bh = *(const half8v*)&Bs[t][cb * 16 + fm][fq * 8];
        acc[t][cb] = __builtin_amdgcn_mfma_f32_16x16x32_f16(ah, bh, acc[t][cb], 0, 0, 0);
      }
    __syncthreads();
  }
  int row0 = bm + wave * 16 + fq * 4;
#pragma unroll
  for (int t = 0; t < 2; ++t) {
    int headi = blockIdx.x * 2 + t;
    int cbase = bn + t * 64;
    float asv[4], adv[4];
#pragma unroll
    for (int cb = 0; cb < 4; ++cb) {
      int col = cbase + cb * 16 + fm;
      asv[cb] = att_s[col];
      adv[cb] = att_d[col];
    }
#pragma unroll
    for (int r = 0; r < 4; ++r) {
      int row = row0 + r;
      float sp = 0.f, dp = 0.f;
#pragma unroll
      for (int cb = 0; cb < 4; ++cb) {
        float v = acc[t][cb][r];
        sp = fmaf(v, asv[cb], sp);
        dp = fmaf(v, adv[cb], dp);
        if (row < M) C[(long)row * 256 + cbase + cb * 16 + fm] = (_Float16)v;
      }
#pragma unroll
      for (int o = 1; o < 16; o <<= 1) {
        sp += __shfl_xor(sp, o);
        dp += __shfl_xor(dp, o);
      }
      if (fm == 0 && row < M) {
        a_s[(long)row * 4 + headi] = sp;
        a_d[(long)row * 4 + headi] = dp;
      }
    }
  }
}

// ---------------- fused fp16 MFMA head ----------------
__launch_bounds__(256)
__global__ void head_mfma_kernel(const _Float16* __restrict__ A, const _Float16* __restrict__ B,
                                 const float* __restrict__ lb1, const float* __restrict__ lw2,
                                 const float* __restrict__ lb2, float* __restrict__ out, int M) {
  __shared__ _Float16 As[64][40];
  __shared__ _Float16 Bs[64][40];
  int tid = threadIdx.x;
  int bm = blockIdx.x * 64;
  int lane = tid & 63, wave = tid >> 6;
  int srow = tid >> 2, sch = (tid & 3) * 8;
  const _Float16* Ap = A + (long)(bm + srow) * 256 + sch;
  const _Float16* Bp = B + (long)srow * 256 + sch;
  int fm = lane & 15, fq = lane >> 4;
  f32x4 acc[4];
#pragma unroll
  for (int cb = 0; cb < 4; ++cb) acc[cb] = (f32x4){0.f, 0.f, 0.f, 0.f};
  for (int k0 = 0; k0 < 256; k0 += 32) {
    uint4 va = *(const uint4*)(Ap + k0);
    uint4 vb = *(const uint4*)(Bp + k0);
    *(uint4*)&As[srow][sch] = va;
    *(uint4*)&Bs[srow][sch] = vb;
    __syncthreads();
    half8v ah = *(const half8v*)&As[wave * 16 + fm][fq * 8];
#pragma unroll
    for (int cb = 0; cb < 4; ++cb) {
      half8v bh = *(const half8v*)&Bs[cb * 16 + fm][fq * 8];
      acc[cb] = __builtin_amdgcn_mfma_f32_16x16x32_f16(ah, bh, acc[cb], 0, 0, 0);
    }
    __syncthreads();
  }
  float lb1c[4], w20[4], w21[4];
#pragma unroll
  for (int cb = 0; cb < 4; ++cb) {
    int col = cb * 16 + fm;
    lb1c[cb] = lb1[col];
    w20[cb] = lw2[col * 2 + 0];
    w21[cb] = lw2[col * 2 + 1];
  }
  float b20 = lb2[0], b21 = lb2[1];
#pragma unroll
  for (int r = 0; r < 4; ++r) {
    float v0 = 0.f, v1 = 0.f;
#pragma unroll
    for (int cb = 0; cb < 4; ++cb) {
      float s = fmaxf(acc[cb][r] + lb1c[cb], 0.f);
      v0 = fmaf(s, w20[cb], v0);
      v1 = fmaf(s, w21[cb], v1);
    }
#pragma unroll
    for (int o = 1; o < 16; o <<= 1) {
      v0 += __shfl_xor(v0, o);
      v1 += __shfl_xor(v1, o);
    }
    if (fm == 0) {
      int row = bm + wave * 16 + fq * 4 + r;
      if (row < M) {
        v0 += b20;
        v1 += b21;
        float mx = fmaxf(v0, v1);
        float ls = mx + logf(expf(v0 - mx) + expf(v1 - mx));
        out[(long)row * 2 + 0] = v0 - ls;
        out[(long)row * 2 + 1] = v1 - ls;
      }
    }
  }
}

// ---------------- per-node ONLINE-softmax aggregation, fp16 gather ----------
__launch_bounds__(256)
__global__ void gat_aggregate8_kernel(const _Float16* __restrict__ h,
                                      const float* __restrict__ a_s,
                                      const float* __restrict__ a_d,
                                      const int* __restrict__ off,
                                      const int* __restrict__ csr_src,
                                      const float* __restrict__ bias,
                                      _Float16* __restrict__ outp, int N) {
  int wid = (blockIdx.x * blockDim.x + threadIdx.x) >> 6;
  int lane = threadIdx.x & 63;
  if (wid >= N) return;
  int c = lane & 31, hlf = lane >> 5, head4 = c >> 3;
  int h1 = lane & 3, sl1 = lane >> 2;
  int beg = off[wid], cnt = off[wid + 1] - beg;
  float ad_h1 = a_d[wid * 4 + h1];
  float m = lrelu(a_s[wid * 4 + h1] + ad_h1);  // running max, init = self logit
  float acc[8] = {};
  float z = 0.f;
  if (hlf == 0) {
    z = 1.f;
    half8v sr = *(const half8v*)(h + (long)wid * 256 + c * 8);
#pragma unroll
    for (int i = 0; i < 8; ++i) acc[i] = (float)sr[i];
  }
  for (int c0 = 0; c0 < cnt; c0 += 16) {
    int i2 = c0 + (lane & 15);
    int sv = (i2 < cnt) ? csr_src[beg + i2] : 0;
    int i1 = c0 + sl1;
    int spi = __shfl(sv, sl1);
    float l = (i1 < cnt) ? lrelu(a_s[(long)spi * 4 + h1] + ad_h1) : -1e30f;
    float lm = l;
    lm = fmaxf(lm, __shfl_xor(lm, 4));
    lm = fmaxf(lm, __shfl_xor(lm, 8));
    lm = fmaxf(lm, __shfl_xor(lm, 16));
    lm = fmaxf(lm, __shfl_xor(lm, 32));
    float m_new = fmaxf(m, lm);
    float alpha = __expf(m - m_new);
    float pv = (i1 < cnt) ? __expf(l - m_new) : 0.f;
    m = m_new;
    float alpha4 = __shfl(alpha, head4);
    z *= alpha4;
#pragma unroll
    for (int i = 0; i < 8; ++i) acc[i] *= alpha4;
#pragma unroll 4
    for (int j = 0; j < 16; j += 2) {
      if (c0 + j >= cnt) break;
      int e = j + hlf;
      int s = __shfl(sv, e);
      float p = __shfl(pv, e * 4 + head4);
      z += p;
      half8v rv = *(const half8v*)(h + (long)s * 256 + c * 8);
      acc[0] = fmaf(p, (float)rv[0], acc[0]);
      acc[1] = fmaf(p, (float)rv[1], acc[1]);
      acc[2] = fmaf(p, (float)rv[2], acc[2]);
      acc[3] = fmaf(p, (float)rv[3], acc[3]);
      acc[4] = fmaf(p, (float)rv[4], acc[4]);
      acc[5] = fmaf(p, (float)rv[5], acc[5]);
      acc[6] = fmaf(p, (float)rv[6], acc[6]);
      acc[7] = fmaf(p, (float)rv[7], acc[7]);
    }
  }
  z += __shfl_xor(z, 32);
#pragma unroll
  for (int i = 0; i < 8; ++i) acc[i] += __shfl_xor(acc[i], 32);
  if (hlf == 0) {
    float inv = 1.f / z;
    half8v o;
#pragma unroll
    for (int i = 0; i < 8; ++i) o[i] = (_Float16)elu1(fmaf(acc[i], inv, bias[c * 8 + i]));
    *(half8v*)(outp + (long)wid * 256 + c * 8) = o;
  }
}

// ---------------------------------------------------------------------------
static inline int cdiv(int a, int b) { return (a + b - 1) / b; }

extern "C" void kernel_launch(void* const* d_in, const int* in_sizes, int n_in,
                              void* d_out, int out_size, void* d_ws, size_t ws_size,
                              hipStream_t stream) {
  const float* x = (const float*)d_in[0];
  const int* ei = (const int*)d_in[1];
  const float* W1 = (const float*)d_in[2];
  const float* as1 = (const float*)d_in[3];
  const float* ad1 = (const float*)d_in[4];
  const float* b1 = (const float*)d_in[5];
  const float* W2 = (const float*)d_in[6];
  const float* as2 = (const float*)d_in[7];
  const float* ad2 = (const float*)d_in[8];
  const float* b2 = (const float*)d_in[9];
  const float* lw1 = (const float*)d_in[10];
  const float* lb1 = (const float*)d_in[11];
  const float* lw2 = (const float*)d_in[12];
  const float* lb2 = (const float*)d_in[13];
  float* out = (float*)d_out;

  int N = in_sizes[0] / 128;  // 50000
  int E = in_sizes[1] / 2;    // 800000
  int Mp = cdiv(N, 64) * 64;  // 50048

  char* ws = (char*)d_ws;
  _Float16* Wt1 = (_Float16*)ws; ws += 256 * 128 * 2;
  _Float16* Wt2 = (_Float16*)ws; ws += 256 * 256 * 2;
  _Float16* WL = (_Float16*)ws; ws += 64 * 256 * 2;
  _Float16* C = (_Float16*)ws; ws += (size_t)Mp * 256 * 2;   // GEMM out
  _Float16* h2 = (_Float16*)ws; ws += (size_t)Mp * 256 * 2;  // aggregate out
  float* aS = (float*)ws; ws += (size_t)N * 4 * 4;
  float* aD = (float*)ws; ws += (size_t)N * 4 * 4;
  int* csr_src = (int*)ws; ws += (size_t)E * 4;
  int* indeg = (int*)ws; ws += (size_t)N * 4;
  int* cursor = (int*)ws; ws += (size_t)N * 4;
  int* off = (int*)ws; ws += (size_t)(N + 4) * 4;
  int* incl = (int*)ws; ws += (size_t)N * 4;
  int* bsum = (int*)ws; ws += 64 * 4;

  const int* e_src = ei;
  const int* e_dst = ei + E;
  int nb = cdiv(N, 1024);

  // weight conversion + indeg zeroing (one launch)
  convert_weights_kernel<<<cdiv(114688 + N, 256), 256, 0, stream>>>(W1, W2, lw1, Wt1, Wt2, WL,
                                                                    indeg, N);

  // CSR build
  count_kernel<<<cdiv(E, 256), 256, 0, stream>>>(e_dst, E, indeg);
  scan_block_kernel<<<nb, 1024, 0, stream>>>(indeg, incl, bsum, N);
  scan_finalize_kernel<<<cdiv(N, 256), 256, 0, stream>>>(indeg, incl, bsum, off, cursor, N);
  fill_kernel<<<cdiv(E, 256), 256, 0, stream>>>(e_src, e_dst, E, cursor, csr_src);

  // Layer 1 (A = fp32 x, converted in staging; 2 head blocks per block)
  mfma_gemm_attn_kernel<float><<<dim3(2, Mp / 64), 256, 0, stream>>>(x, Wt1, as1, ad1, C, aS, aD,
                                                                     N, 128);
  gat_aggregate8_kernel<<<cdiv(N, 4), 256, 0, stream>>>(C, aS, aD, off, csr_src, b1, h2, N);

  // Layer 2
  mfma_gemm_attn_kernel<_Float16><<<dim3(2, Mp / 64), 256, 0, stream>>>(h2, Wt2, as2, ad2, C, aS,
                                                                        aD, N, 256);
  gat_aggregate8_kernel<<<cdiv(N, 4), 256, 0, stream>>>(C, aS, aD, off, csr_src, b2, h2, N);

  // Head (MFMA, fused epilogue)
  head_mfma_kernel<<<Mp / 64, 256, 0, stream>>>(h2, WL, lb1, lw2, lb2, out, N);
}